// Round 1
// baseline (1006.477 us; speedup 1.0000x reference)
//
#include <hip/hip_runtime.h>
#include <stdint.h>

#define D_FEAT 64
#define K_LAYERS 10
#define SCAN_CHUNK 2048

// ---------------- degree histogram ----------------
__global__ void deg_kernel(const int* __restrict__ src, const int* __restrict__ dst,
                           int* deg_out, int* deg_in, int E) {
    int i = blockIdx.x * blockDim.x + threadIdx.x;
    if (i < E) {
        atomicAdd(&deg_out[src[i]], 1);
        atomicAdd(&deg_in[dst[i]], 1);
    }
}

// ---------------- norms ----------------
__global__ void norm_kernel(const int* __restrict__ deg_out, const int* __restrict__ deg_in,
                            float* __restrict__ ns, float* __restrict__ nd, int N) {
    int i = blockIdx.x * blockDim.x + threadIdx.x;
    if (i < N) {
        ns[i] = rsqrtf(fmaxf((float)deg_out[i], 1.0f));
        nd[i] = rsqrtf(fmaxf((float)deg_in[i], 1.0f));
    }
}

// ---------------- scan (3 stages) for row_ptr = exclusive_scan(deg_in) ----------------
__global__ void chunk_sum_kernel(const int* __restrict__ deg, int N, int* __restrict__ partials) {
    __shared__ int sdata[256];
    constexpr int PT = SCAN_CHUNK / 256;
    int base = blockIdx.x * SCAN_CHUNK;
    int t = threadIdx.x;
    int s = 0;
#pragma unroll
    for (int j = 0; j < PT; ++j) {
        int idx = base + t * PT + j;
        if (idx < N) s += deg[idx];
    }
    sdata[t] = s;
    __syncthreads();
    for (int off = 128; off > 0; off >>= 1) {
        if (t < off) sdata[t] += sdata[t + off];
        __syncthreads();
    }
    if (t == 0) partials[blockIdx.x] = sdata[0];
}

__global__ void scan_partials_kernel(int* partials, int nchunks, int* row_ptr, int N, int E) {
    if (threadIdx.x == 0 && blockIdx.x == 0) {
        int s = 0;
        for (int i = 0; i < nchunks; ++i) { int v = partials[i]; partials[i] = s; s += v; }
        row_ptr[N] = E;
    }
}

__global__ void chunk_scan_kernel(const int* __restrict__ deg, int N,
                                  const int* __restrict__ partials, int* __restrict__ row_ptr) {
    __shared__ int sdata[256];
    constexpr int PT = SCAN_CHUNK / 256;
    int base = blockIdx.x * SCAN_CHUNK;
    int t = threadIdx.x;
    int vals[PT];
    int s = 0;
#pragma unroll
    for (int j = 0; j < PT; ++j) {
        int idx = base + t * PT + j;
        int v = (idx < N) ? deg[idx] : 0;
        vals[j] = s;   // local exclusive prefix
        s += v;
    }
    sdata[t] = s;
    __syncthreads();
    // Hillis-Steele inclusive scan over 256 thread sums
    for (int off = 1; off < 256; off <<= 1) {
        int v = (t >= off) ? sdata[t - off] : 0;
        __syncthreads();
        sdata[t] += v;
        __syncthreads();
    }
    int texcl = (t > 0) ? sdata[t - 1] : 0;
    int off0 = partials[blockIdx.x];
#pragma unroll
    for (int j = 0; j < PT; ++j) {
        int idx = base + t * PT + j;
        if (idx < N) row_ptr[idx] = off0 + texcl + vals[j];
    }
}

// ---------------- CSR edge fill: (src, w) records sorted by dst ----------------
__global__ void fill_kernel(const int* __restrict__ src, const int* __restrict__ dst,
                            const float* __restrict__ ns, const float* __restrict__ nd,
                            const int* __restrict__ row_ptr, int* cursor,
                            uint2* __restrict__ edges, int E) {
    int i = blockIdx.x * blockDim.x + threadIdx.x;
    if (i < E) {
        int d = dst[i];
        int s = src[i];
        int pos = row_ptr[d] + atomicAdd(&cursor[d], 1);
        float w = ns[s] * nd[d];
        edges[pos] = make_uint2((unsigned)s, __float_as_uint(w));
    }
}

// ---------------- propagation: one wave per node, lane = feature dim ----------------
__global__ __launch_bounds__(256) void prop_kernel(
    const float* __restrict__ h, const float* __restrict__ h0,
    const uint2* __restrict__ edges, const int* __restrict__ row_ptr,
    float* __restrict__ out, int N)
{
    int gid  = blockIdx.x * blockDim.x + threadIdx.x;
    int node = gid >> 6;
    int lane = threadIdx.x & 63;
    if (node >= N) return;

    int start = row_ptr[node];
    int end   = row_ptr[node + 1];

    float acc = 0.f;
    int e = start;
    for (; e + 4 <= end; e += 4) {
        uint2 c0 = edges[e + 0];
        uint2 c1 = edges[e + 1];
        uint2 c2 = edges[e + 2];
        uint2 c3 = edges[e + 3];
        float v0 = h[(c0.x << 6) + lane];
        float v1 = h[(c1.x << 6) + lane];
        float v2 = h[(c2.x << 6) + lane];
        float v3 = h[(c3.x << 6) + lane];
        acc += __uint_as_float(c0.y) * v0;
        acc += __uint_as_float(c1.y) * v1;
        acc += __uint_as_float(c2.y) * v2;
        acc += __uint_as_float(c3.y) * v3;
    }
    for (; e < end; ++e) {
        uint2 c = edges[e];
        acc += __uint_as_float(c.y) * h[(c.x << 6) + lane];
    }

    int o = (node << 6) + lane;
    out[o] = 0.9f * acc + 0.1f * h0[o];
}

extern "C" void kernel_launch(void* const* d_in, const int* in_sizes, int n_in,
                              void* d_out, int out_size, void* d_ws, size_t ws_size,
                              hipStream_t stream) {
    const float* features = (const float*)d_in[0];
    const int*   src      = (const int*)d_in[1];
    const int*   dst      = (const int*)d_in[2];
    const int E = in_sizes[1];
    const int N = in_sizes[0] / D_FEAT;

    // ---- workspace layout ----
    char* ws = (char*)d_ws;
    size_t off = 0;
    auto alloc = [&](size_t bytes, size_t align) -> char* {
        off = (off + align - 1) & ~(align - 1);
        char* p = ws + off;
        off += bytes;
        return p;
    };
    int*   deg_out = (int*)alloc(4 * (size_t)N, 4);
    int*   deg_in  = (int*)alloc(4 * (size_t)N, 4);
    int*   cursor  = (int*)alloc(4 * (size_t)N, 4);
    int*   row_ptr = (int*)alloc(4 * ((size_t)N + 1), 4);
    float* ns      = (float*)alloc(4 * (size_t)N, 4);
    float* nd      = (float*)alloc(4 * (size_t)N, 4);
    int nchunks = (N + SCAN_CHUNK - 1) / SCAN_CHUNK;
    int*   partials = (int*)alloc(4 * (size_t)nchunks, 4);
    uint2* edges   = (uint2*)alloc(8 * (size_t)E, 8);
    float* h_ws    = (float*)alloc(4 * (size_t)N * D_FEAT, 4);

    // deg_out, deg_in, cursor are contiguous -> single memset
    hipMemsetAsync(deg_out, 0, 4 * (size_t)N * 3, stream);

    deg_kernel<<<(E + 255) / 256, 256, 0, stream>>>(src, dst, deg_out, deg_in, E);
    norm_kernel<<<(N + 255) / 256, 256, 0, stream>>>(deg_out, deg_in, ns, nd, N);
    chunk_sum_kernel<<<nchunks, 256, 0, stream>>>(deg_in, N, partials);
    scan_partials_kernel<<<1, 64, 0, stream>>>(partials, nchunks, row_ptr, N, E);
    chunk_scan_kernel<<<nchunks, 256, 0, stream>>>(deg_in, N, partials, row_ptr);
    fill_kernel<<<(E + 255) / 256, 256, 0, stream>>>(src, dst, ns, nd, row_ptr, cursor, edges, E);

    // ---- K layers of propagation, ping-pong ws <-> d_out (K even => last lands in d_out)
    float* outp = (float*)d_out;
    const float* h_in = features;
    int prop_blocks = ((size_t)N * 64 + 255) / 256;
    for (int k = 0; k < K_LAYERS; ++k) {
        float* h_out = (k & 1) ? outp : h_ws;
        prop_kernel<<<prop_blocks, 256, 0, stream>>>(h_in, features, edges, row_ptr, h_out, N);
        h_in = h_out;
    }
}

// Round 2
// 940.259 us; speedup vs baseline: 1.0704x; 1.0704x over previous
//
#include <hip/hip_runtime.h>
#include <stdint.h>

#define D_FEAT 64
#define K_LAYERS 10
#define SCAN_CHUNK 2048

// ---------------- degree histogram (4 edges/thread, int4 loads) ----------------
__global__ void deg_kernel(const int* __restrict__ src, const int* __restrict__ dst,
                           int* deg_out, int* deg_in, int E) {
    int i = blockIdx.x * blockDim.x + threadIdx.x;
    int base = i * 4;
    if (base + 3 < E) {
        int4 s4 = *(const int4*)(src + base);
        int4 d4 = *(const int4*)(dst + base);
        atomicAdd(&deg_out[s4.x], 1); atomicAdd(&deg_in[d4.x], 1);
        atomicAdd(&deg_out[s4.y], 1); atomicAdd(&deg_in[d4.y], 1);
        atomicAdd(&deg_out[s4.z], 1); atomicAdd(&deg_in[d4.z], 1);
        atomicAdd(&deg_out[s4.w], 1); atomicAdd(&deg_in[d4.w], 1);
    } else {
        for (int j = base; j < E; ++j) {
            atomicAdd(&deg_out[src[j]], 1);
            atomicAdd(&deg_in[dst[j]], 1);
        }
    }
}

// ---------------- norms ----------------
__global__ void norm_kernel(const int* __restrict__ deg_out, const int* __restrict__ deg_in,
                            float* __restrict__ ns, float* __restrict__ nd, int N) {
    int i = blockIdx.x * blockDim.x + threadIdx.x;
    if (i < N) {
        ns[i] = rsqrtf(fmaxf((float)deg_out[i], 1.0f));
        nd[i] = rsqrtf(fmaxf((float)deg_in[i], 1.0f));
    }
}

// ---------------- scan (3 stages) for row_ptr = exclusive_scan(deg_in) ----------------
__global__ void chunk_sum_kernel(const int* __restrict__ deg, int N, int* __restrict__ partials) {
    __shared__ int sdata[256];
    constexpr int PT = SCAN_CHUNK / 256;
    int base = blockIdx.x * SCAN_CHUNK;
    int t = threadIdx.x;
    int s = 0;
#pragma unroll
    for (int j = 0; j < PT; ++j) {
        int idx = base + t * PT + j;
        if (idx < N) s += deg[idx];
    }
    sdata[t] = s;
    __syncthreads();
    for (int off = 128; off > 0; off >>= 1) {
        if (t < off) sdata[t] += sdata[t + off];
        __syncthreads();
    }
    if (t == 0) partials[blockIdx.x] = sdata[0];
}

__global__ void scan_partials_kernel(int* partials, int nchunks, int* row_ptr, int N, int E) {
    if (threadIdx.x == 0 && blockIdx.x == 0) {
        int s = 0;
        for (int i = 0; i < nchunks; ++i) { int v = partials[i]; partials[i] = s; s += v; }
        row_ptr[N] = E;
    }
}

__global__ void chunk_scan_kernel(const int* __restrict__ deg, int N,
                                  const int* __restrict__ partials, int* __restrict__ row_ptr) {
    __shared__ int sdata[256];
    constexpr int PT = SCAN_CHUNK / 256;
    int base = blockIdx.x * SCAN_CHUNK;
    int t = threadIdx.x;
    int vals[PT];
    int s = 0;
#pragma unroll
    for (int j = 0; j < PT; ++j) {
        int idx = base + t * PT + j;
        int v = (idx < N) ? deg[idx] : 0;
        vals[j] = s;   // local exclusive prefix
        s += v;
    }
    sdata[t] = s;
    __syncthreads();
    for (int off = 1; off < 256; off <<= 1) {
        int v = (t >= off) ? sdata[t - off] : 0;
        __syncthreads();
        sdata[t] += v;
        __syncthreads();
    }
    int texcl = (t > 0) ? sdata[t - 1] : 0;
    int off0 = partials[blockIdx.x];
#pragma unroll
    for (int j = 0; j < PT; ++j) {
        int idx = base + t * PT + j;
        if (idx < N) row_ptr[idx] = off0 + texcl + vals[j];
    }
}

// ---------------- CSR edge fill: (src, w) records sorted by dst ----------------
__global__ void fill_kernel(const int* __restrict__ src, const int* __restrict__ dst,
                            const float* __restrict__ ns, const float* __restrict__ nd,
                            const int* __restrict__ row_ptr, int* cursor,
                            uint2* __restrict__ edges, int E) {
    int i = blockIdx.x * blockDim.x + threadIdx.x;
    int base = i * 4;
    if (base + 3 < E) {
        int4 s4 = *(const int4*)(src + base);
        int4 d4 = *(const int4*)(dst + base);
#pragma unroll
        for (int j = 0; j < 4; ++j) {
            int s = (j == 0) ? s4.x : (j == 1) ? s4.y : (j == 2) ? s4.z : s4.w;
            int d = (j == 0) ? d4.x : (j == 1) ? d4.y : (j == 2) ? d4.z : d4.w;
            int pos = row_ptr[d] + atomicAdd(&cursor[d], 1);
            float w = ns[s] * nd[d];
            edges[pos] = make_uint2((unsigned)s, __float_as_uint(w));
        }
    } else {
        for (int j = base; j < E; ++j) {
            int d = dst[j];
            int s = src[j];
            int pos = row_ptr[d] + atomicAdd(&cursor[d], 1);
            float w = ns[s] * nd[d];
            edges[pos] = make_uint2((unsigned)s, __float_as_uint(w));
        }
    }
}

// ---------------- propagation ----------------
// One wave per node. 4 groups x 16 lanes; each lane holds float4 (16 lanes = 64 feats).
// Group g processes edges start+g, start+g+4, ... -> one dwordx4 gather instruction
// carries 1KB covering 4 edges. x2 unroll => up to 8 edges (2KB) in flight per wave.
__global__ __launch_bounds__(256) void prop_kernel(
    const float* __restrict__ h, const float* __restrict__ h0,
    const uint2* __restrict__ edges, const int* __restrict__ row_ptr,
    float* __restrict__ out, int N)
{
    int gid  = blockIdx.x * blockDim.x + threadIdx.x;
    int node = gid >> 6;
    if (node >= N) return;
    int lane = threadIdx.x & 63;
    int grp  = lane >> 4;   // 0..3  : which edge of the quad
    int fl   = lane & 15;   // float4 slot within the node row

    int start = row_ptr[node];
    int end   = row_ptr[node + 1];

    float4 acc = make_float4(0.f, 0.f, 0.f, 0.f);

    int e = start + grp;
    // two edges per group per iteration (8 edges per wave iteration)
    for (; e + 4 < end; e += 8) {
        uint2 r0 = edges[e];
        uint2 r1 = edges[e + 4];
        float4 v0 = *((const float4*)(h + ((size_t)r0.x << 6)) + fl);
        float4 v1 = *((const float4*)(h + ((size_t)r1.x << 6)) + fl);
        float w0 = __uint_as_float(r0.y);
        float w1 = __uint_as_float(r1.y);
        acc.x = fmaf(w0, v0.x, acc.x);
        acc.y = fmaf(w0, v0.y, acc.y);
        acc.z = fmaf(w0, v0.z, acc.z);
        acc.w = fmaf(w0, v0.w, acc.w);
        acc.x = fmaf(w1, v1.x, acc.x);
        acc.y = fmaf(w1, v1.y, acc.y);
        acc.z = fmaf(w1, v1.z, acc.z);
        acc.w = fmaf(w1, v1.w, acc.w);
    }
    if (e < end) {
        uint2 r0 = edges[e];
        float4 v0 = *((const float4*)(h + ((size_t)r0.x << 6)) + fl);
        float w0 = __uint_as_float(r0.y);
        acc.x = fmaf(w0, v0.x, acc.x);
        acc.y = fmaf(w0, v0.y, acc.y);
        acc.z = fmaf(w0, v0.z, acc.z);
        acc.w = fmaf(w0, v0.w, acc.w);
    }

    // reduce across the 4 groups (lane ^ 16, lane ^ 32)
    acc.x += __shfl_xor(acc.x, 16, 64);
    acc.y += __shfl_xor(acc.y, 16, 64);
    acc.z += __shfl_xor(acc.z, 16, 64);
    acc.w += __shfl_xor(acc.w, 16, 64);
    acc.x += __shfl_xor(acc.x, 32, 64);
    acc.y += __shfl_xor(acc.y, 32, 64);
    acc.z += __shfl_xor(acc.z, 32, 64);
    acc.w += __shfl_xor(acc.w, 32, 64);

    if (grp == 0) {
        float4 b = *((const float4*)(h0 + ((size_t)node << 6)) + fl);
        float4 r;
        r.x = fmaf(0.9f, acc.x, 0.1f * b.x);
        r.y = fmaf(0.9f, acc.y, 0.1f * b.y);
        r.z = fmaf(0.9f, acc.z, 0.1f * b.z);
        r.w = fmaf(0.9f, acc.w, 0.1f * b.w);
        *((float4*)(out + ((size_t)node << 6)) + fl) = r;
    }
}

extern "C" void kernel_launch(void* const* d_in, const int* in_sizes, int n_in,
                              void* d_out, int out_size, void* d_ws, size_t ws_size,
                              hipStream_t stream) {
    const float* features = (const float*)d_in[0];
    const int*   src      = (const int*)d_in[1];
    const int*   dst      = (const int*)d_in[2];
    const int E = in_sizes[1];
    const int N = in_sizes[0] / D_FEAT;

    // ---- workspace layout ----
    char* ws = (char*)d_ws;
    size_t off = 0;
    auto alloc = [&](size_t bytes, size_t align) -> char* {
        off = (off + align - 1) & ~(align - 1);
        char* p = ws + off;
        off += bytes;
        return p;
    };
    int*   deg_out = (int*)alloc(4 * (size_t)N, 4);
    int*   deg_in  = (int*)alloc(4 * (size_t)N, 4);
    int*   cursor  = (int*)alloc(4 * (size_t)N, 4);
    int*   row_ptr = (int*)alloc(4 * ((size_t)N + 1), 4);
    float* ns      = (float*)alloc(4 * (size_t)N, 4);
    float* nd      = (float*)alloc(4 * (size_t)N, 4);
    int nchunks = (N + SCAN_CHUNK - 1) / SCAN_CHUNK;
    int*   partials = (int*)alloc(4 * (size_t)nchunks, 4);
    uint2* edges   = (uint2*)alloc(8 * (size_t)E, 8);
    float* h_ws    = (float*)alloc(4 * (size_t)N * D_FEAT, 16);

    // deg_out, deg_in, cursor are contiguous -> single memset
    hipMemsetAsync(deg_out, 0, 4 * (size_t)N * 3, stream);

    int ethreads4 = (E + 3) / 4;
    deg_kernel<<<(ethreads4 + 255) / 256, 256, 0, stream>>>(src, dst, deg_out, deg_in, E);
    norm_kernel<<<(N + 255) / 256, 256, 0, stream>>>(deg_out, deg_in, ns, nd, N);
    chunk_sum_kernel<<<nchunks, 256, 0, stream>>>(deg_in, N, partials);
    scan_partials_kernel<<<1, 64, 0, stream>>>(partials, nchunks, row_ptr, N, E);
    chunk_scan_kernel<<<nchunks, 256, 0, stream>>>(deg_in, N, partials, row_ptr);
    fill_kernel<<<(ethreads4 + 255) / 256, 256, 0, stream>>>(src, dst, ns, nd, row_ptr, cursor, edges, E);

    // ---- K layers of propagation, ping-pong ws <-> d_out (K even => last lands in d_out)
    float* outp = (float*)d_out;
    const float* h_in = features;
    int prop_blocks = (int)(((size_t)N * 64 + 255) / 256);
    for (int k = 0; k < K_LAYERS; ++k) {
        float* h_out = (k & 1) ? outp : h_ws;
        prop_kernel<<<prop_blocks, 256, 0, stream>>>(h_in, features, edges, row_ptr, h_out, N);
        h_in = h_out;
    }
}

// Round 3
// 759.141 us; speedup vs baseline: 1.3258x; 1.2386x over previous
//
#include <hip/hip_runtime.h>
#include <hip/hip_fp16.h>
#include <stdint.h>

#define D_FEAT 64
#define K_LAYERS 10
#define SCAN_CHUNK 2048

// ---------------- degree histogram (4 edges/thread, int4 loads) ----------------
__global__ void deg_kernel(const int* __restrict__ src, const int* __restrict__ dst,
                           int* deg_out, int* deg_in, int E) {
    int i = blockIdx.x * blockDim.x + threadIdx.x;
    int base = i * 4;
    if (base + 3 < E) {
        int4 s4 = *(const int4*)(src + base);
        int4 d4 = *(const int4*)(dst + base);
        atomicAdd(&deg_out[s4.x], 1); atomicAdd(&deg_in[d4.x], 1);
        atomicAdd(&deg_out[s4.y], 1); atomicAdd(&deg_in[d4.y], 1);
        atomicAdd(&deg_out[s4.z], 1); atomicAdd(&deg_in[d4.z], 1);
        atomicAdd(&deg_out[s4.w], 1); atomicAdd(&deg_in[d4.w], 1);
    } else {
        for (int j = base; j < E; ++j) {
            atomicAdd(&deg_out[src[j]], 1);
            atomicAdd(&deg_in[dst[j]], 1);
        }
    }
}

// ---------------- norms ----------------
__global__ void norm_kernel(const int* __restrict__ deg_out, const int* __restrict__ deg_in,
                            float* __restrict__ ns, float* __restrict__ nd, int N) {
    int i = blockIdx.x * blockDim.x + threadIdx.x;
    if (i < N) {
        ns[i] = rsqrtf(fmaxf((float)deg_out[i], 1.0f));
        nd[i] = rsqrtf(fmaxf((float)deg_in[i], 1.0f));
    }
}

// ---------------- features fp32 -> fp16 ----------------
__global__ void cvt_kernel(const float* __restrict__ in, __half* __restrict__ out, int n8) {
    int i = blockIdx.x * blockDim.x + threadIdx.x;
    if (i < n8) {
        float4 a = *((const float4*)in + 2 * i);
        float4 b = *((const float4*)in + 2 * i + 1);
        __half2 o[4];
        o[0] = __float22half2_rn(make_float2(a.x, a.y));
        o[1] = __float22half2_rn(make_float2(a.z, a.w));
        o[2] = __float22half2_rn(make_float2(b.x, b.y));
        o[3] = __float22half2_rn(make_float2(b.z, b.w));
        *((float4*)out + i) = *(const float4*)o;
    }
}

// ---------------- scan (3 stages) for row_ptr = exclusive_scan(deg_in) ----------------
__global__ void chunk_sum_kernel(const int* __restrict__ deg, int N, int* __restrict__ partials) {
    __shared__ int sdata[256];
    constexpr int PT = SCAN_CHUNK / 256;
    int base = blockIdx.x * SCAN_CHUNK;
    int t = threadIdx.x;
    int s = 0;
#pragma unroll
    for (int j = 0; j < PT; ++j) {
        int idx = base + t * PT + j;
        if (idx < N) s += deg[idx];
    }
    sdata[t] = s;
    __syncthreads();
    for (int off = 128; off > 0; off >>= 1) {
        if (t < off) sdata[t] += sdata[t + off];
        __syncthreads();
    }
    if (t == 0) partials[blockIdx.x] = sdata[0];
}

__global__ void scan_partials_kernel(int* partials, int nchunks, int* row_ptr, int N, int E) {
    if (threadIdx.x == 0 && blockIdx.x == 0) {
        int s = 0;
        for (int i = 0; i < nchunks; ++i) { int v = partials[i]; partials[i] = s; s += v; }
        row_ptr[N] = E;
    }
}

__global__ void chunk_scan_kernel(const int* __restrict__ deg, int N,
                                  const int* __restrict__ partials, int* __restrict__ row_ptr) {
    __shared__ int sdata[256];
    constexpr int PT = SCAN_CHUNK / 256;
    int base = blockIdx.x * SCAN_CHUNK;
    int t = threadIdx.x;
    int vals[PT];
    int s = 0;
#pragma unroll
    for (int j = 0; j < PT; ++j) {
        int idx = base + t * PT + j;
        int v = (idx < N) ? deg[idx] : 0;
        vals[j] = s;
        s += v;
    }
    sdata[t] = s;
    __syncthreads();
    for (int off = 1; off < 256; off <<= 1) {
        int v = (t >= off) ? sdata[t - off] : 0;
        __syncthreads();
        sdata[t] += v;
        __syncthreads();
    }
    int texcl = (t > 0) ? sdata[t - 1] : 0;
    int off0 = partials[blockIdx.x];
#pragma unroll
    for (int j = 0; j < PT; ++j) {
        int idx = base + t * PT + j;
        if (idx < N) row_ptr[idx] = off0 + texcl + vals[j];
    }
}

// ---------------- CSR edge fill: cursor pre-initialized to row_ptr ----------------
__global__ void fill_kernel(const int* __restrict__ src, const int* __restrict__ dst,
                            const float* __restrict__ ns, const float* __restrict__ nd,
                            int* cursor, uint2* __restrict__ edges, int E) {
    int i = blockIdx.x * blockDim.x + threadIdx.x;
    int base = i * 4;
    if (base + 3 < E) {
        int4 s4 = *(const int4*)(src + base);
        int4 d4 = *(const int4*)(dst + base);
#pragma unroll
        for (int j = 0; j < 4; ++j) {
            int s = (j == 0) ? s4.x : (j == 1) ? s4.y : (j == 2) ? s4.z : s4.w;
            int d = (j == 0) ? d4.x : (j == 1) ? d4.y : (j == 2) ? d4.z : d4.w;
            int pos = atomicAdd(&cursor[d], 1);
            float w = ns[s] * nd[d];
            edges[pos] = make_uint2((unsigned)s, __float_as_uint(w));
        }
    } else {
        for (int j = base; j < E; ++j) {
            int d = dst[j];
            int s = src[j];
            int pos = atomicAdd(&cursor[d], 1);
            float w = ns[s] * nd[d];
            edges[pos] = make_uint2((unsigned)s, __float_as_uint(w));
        }
    }
}

// ---------------- propagation (fp16 h storage, fp32 accumulate) ----------------
// One wave per node. 8 groups x 8 lanes; each lane loads float4 = 8 halves
// (8 lanes x 16B = one 128B fp16 node row). One gather instruction covers 8 edges.
template <bool LAST>
__global__ __launch_bounds__(256) void prop_kernel(
    const __half* __restrict__ h, const __half* __restrict__ h0,
    const uint2* __restrict__ edges, const int* __restrict__ row_ptr,
    void* __restrict__ out, int N)
{
    int gid  = blockIdx.x * blockDim.x + threadIdx.x;
    int node = gid >> 6;
    if (node >= N) return;
    int lane = threadIdx.x & 63;
    int grp  = lane >> 3;   // 0..7 : which edge of the octet
    int fl   = lane & 7;    // float4 slot within the 128B node row

    int start = row_ptr[node];
    int end   = row_ptr[node + 1];

    float acc[8];
#pragma unroll
    for (int j = 0; j < 8; ++j) acc[j] = 0.f;

    auto do_edge = [&](int e) {
        uint2 r = edges[e];
        float4 raw = *((const float4*)(h + ((size_t)r.x << 6)) + fl);
        float w = __uint_as_float(r.y);
        const __half2* hp = (const __half2*)&raw;
#pragma unroll
        for (int k = 0; k < 4; ++k) {
            float2 f = __half22float2(hp[k]);
            acc[2 * k]     = fmaf(w, f.x, acc[2 * k]);
            acc[2 * k + 1] = fmaf(w, f.y, acc[2 * k + 1]);
        }
    };

    int e = start + grp;
    for (; e + 8 < end; e += 16) {  // 2 edges per group per iter = 16 edges/wave
        uint2 r0 = edges[e];
        uint2 r1 = edges[e + 8];
        float4 v0 = *((const float4*)(h + ((size_t)r0.x << 6)) + fl);
        float4 v1 = *((const float4*)(h + ((size_t)r1.x << 6)) + fl);
        float w0 = __uint_as_float(r0.y);
        float w1 = __uint_as_float(r1.y);
        const __half2* p0 = (const __half2*)&v0;
        const __half2* p1 = (const __half2*)&v1;
#pragma unroll
        for (int k = 0; k < 4; ++k) {
            float2 f0 = __half22float2(p0[k]);
            float2 f1 = __half22float2(p1[k]);
            acc[2 * k]     = fmaf(w0, f0.x, acc[2 * k]);
            acc[2 * k + 1] = fmaf(w0, f0.y, acc[2 * k + 1]);
            acc[2 * k]     = fmaf(w1, f1.x, acc[2 * k]);
            acc[2 * k + 1] = fmaf(w1, f1.y, acc[2 * k + 1]);
        }
    }
    if (e < end) do_edge(e);

    // reduce across the 8 groups
#pragma unroll
    for (int j = 0; j < 8; ++j) acc[j] += __shfl_xor(acc[j], 8, 64);
#pragma unroll
    for (int j = 0; j < 8; ++j) acc[j] += __shfl_xor(acc[j], 16, 64);
#pragma unroll
    for (int j = 0; j < 8; ++j) acc[j] += __shfl_xor(acc[j], 32, 64);

    if (grp == 0) {
        float4 braw = *((const float4*)(h0 + ((size_t)node << 6)) + fl);
        const __half2* bp = (const __half2*)&braw;
        float r[8];
#pragma unroll
        for (int k = 0; k < 4; ++k) {
            float2 f = __half22float2(bp[k]);
            r[2 * k]     = fmaf(0.9f, acc[2 * k],     0.1f * f.x);
            r[2 * k + 1] = fmaf(0.9f, acc[2 * k + 1], 0.1f * f.y);
        }
        if (!LAST) {
            __half2 o[4];
#pragma unroll
            for (int k = 0; k < 4; ++k)
                o[k] = __float22half2_rn(make_float2(r[2 * k], r[2 * k + 1]));
            *((float4*)((__half*)out + ((size_t)node << 6)) + fl) = *(const float4*)o;
        } else {
            float4* op = (float4*)((float*)out + ((size_t)node << 6));
            op[2 * fl]     = make_float4(r[0], r[1], r[2], r[3]);
            op[2 * fl + 1] = make_float4(r[4], r[5], r[6], r[7]);
        }
    }
}

extern "C" void kernel_launch(void* const* d_in, const int* in_sizes, int n_in,
                              void* d_out, int out_size, void* d_ws, size_t ws_size,
                              hipStream_t stream) {
    const float* features = (const float*)d_in[0];
    const int*   src      = (const int*)d_in[1];
    const int*   dst      = (const int*)d_in[2];
    const int E = in_sizes[1];
    const int N = in_sizes[0] / D_FEAT;

    // ---- workspace layout ----
    char* ws = (char*)d_ws;
    size_t off = 0;
    auto alloc = [&](size_t bytes, size_t align) -> char* {
        off = (off + align - 1) & ~(align - 1);
        char* p = ws + off;
        off += bytes;
        return p;
    };
    int*    deg_out = (int*)alloc(4 * (size_t)N, 4);
    int*    deg_in  = (int*)alloc(4 * (size_t)N, 4);
    int*    cursor  = (int*)alloc(4 * (size_t)N, 4);
    int*    row_ptr = (int*)alloc(4 * ((size_t)N + 1), 4);
    float*  ns      = (float*)alloc(4 * (size_t)N, 4);
    float*  nd      = (float*)alloc(4 * (size_t)N, 4);
    int nchunks = (N + SCAN_CHUNK - 1) / SCAN_CHUNK;
    int*    partials = (int*)alloc(4 * (size_t)nchunks, 4);
    uint2*  edges   = (uint2*)alloc(8 * (size_t)E, 16);
    __half* feat16  = (__half*)alloc(2 * (size_t)N * D_FEAT, 16);
    __half* hbufA   = (__half*)alloc(2 * (size_t)N * D_FEAT, 16);
    __half* hbufB   = (__half*)alloc(2 * (size_t)N * D_FEAT, 16);

    // deg_out, deg_in contiguous -> single memset
    hipMemsetAsync(deg_out, 0, 4 * (size_t)N * 2, stream);

    int ethreads4 = (E + 3) / 4;
    deg_kernel<<<(ethreads4 + 255) / 256, 256, 0, stream>>>(src, dst, deg_out, deg_in, E);

    int n8 = N * D_FEAT / 8;
    cvt_kernel<<<(n8 + 255) / 256, 256, 0, stream>>>(features, feat16, n8);

    norm_kernel<<<(N + 255) / 256, 256, 0, stream>>>(deg_out, deg_in, ns, nd, N);
    chunk_sum_kernel<<<nchunks, 256, 0, stream>>>(deg_in, N, partials);
    scan_partials_kernel<<<1, 64, 0, stream>>>(partials, nchunks, row_ptr, N, E);
    chunk_scan_kernel<<<nchunks, 256, 0, stream>>>(deg_in, N, partials, row_ptr);
    hipMemcpyAsync(cursor, row_ptr, 4 * (size_t)N, hipMemcpyDeviceToDevice, stream);
    fill_kernel<<<(ethreads4 + 255) / 256, 256, 0, stream>>>(src, dst, ns, nd, cursor, edges, E);

    // ---- K layers: layers 0..8 write fp16 ping-pong, layer 9 writes fp32 d_out
    const __half* h_in = feat16;
    int prop_blocks = (int)(((size_t)N * 64 + 255) / 256);
    for (int k = 0; k < K_LAYERS - 1; ++k) {
        __half* h_out = (k & 1) ? hbufB : hbufA;
        prop_kernel<false><<<prop_blocks, 256, 0, stream>>>(h_in, feat16, edges, row_ptr, h_out, N);
        h_in = h_out;
    }
    prop_kernel<true><<<prop_blocks, 256, 0, stream>>>(h_in, feat16, edges, row_ptr, d_out, N);
}

// Round 4
// 728.828 us; speedup vs baseline: 1.3810x; 1.0416x over previous
//
#include <hip/hip_runtime.h>
#include <hip/hip_fp16.h>
#include <stdint.h>

#define D_FEAT 64
#define K_LAYERS 10
#define SCAN_CHUNK 2048

// ---------------- degree histogram + dst-rank (4 edges/thread) ----------------
// rank[i] = old value of deg_in[dst[i]] => unique slot within the dst segment.
__global__ void deg_kernel(const int* __restrict__ src, const int* __restrict__ dst,
                           int* deg_out, int* deg_in, int* __restrict__ rank, int E) {
    int i = blockIdx.x * blockDim.x + threadIdx.x;
    int base = i * 4;
    if (base + 3 < E) {
        int4 s4 = *(const int4*)(src + base);
        int4 d4 = *(const int4*)(dst + base);
        atomicAdd(&deg_out[s4.x], 1);
        atomicAdd(&deg_out[s4.y], 1);
        atomicAdd(&deg_out[s4.z], 1);
        atomicAdd(&deg_out[s4.w], 1);
        int4 r;
        r.x = atomicAdd(&deg_in[d4.x], 1);
        r.y = atomicAdd(&deg_in[d4.y], 1);
        r.z = atomicAdd(&deg_in[d4.z], 1);
        r.w = atomicAdd(&deg_in[d4.w], 1);
        *(int4*)(rank + base) = r;
    } else {
        for (int j = base; j < E; ++j) {
            atomicAdd(&deg_out[src[j]], 1);
            rank[j] = atomicAdd(&deg_in[dst[j]], 1);
        }
    }
}

// ---------------- norms: ns, nd, c = 0.9*ns*nd ----------------
__global__ void norm_kernel(const int* __restrict__ deg_out, const int* __restrict__ deg_in,
                            float* __restrict__ ns, float* __restrict__ nd,
                            float* __restrict__ cvec, int N) {
    int i = blockIdx.x * blockDim.x + threadIdx.x;
    if (i < N) {
        float a = rsqrtf(fmaxf((float)deg_out[i], 1.0f));
        float b = rsqrtf(fmaxf((float)deg_in[i], 1.0f));
        ns[i] = a;
        nd[i] = b;
        cvec[i] = 0.9f * a * b;
    }
}

// ---------------- scan (3 stages) for row_ptr = exclusive_scan(deg_in) ----------------
__global__ void chunk_sum_kernel(const int* __restrict__ deg, int N, int* __restrict__ partials) {
    __shared__ int sdata[256];
    constexpr int PT = SCAN_CHUNK / 256;
    int base = blockIdx.x * SCAN_CHUNK;
    int t = threadIdx.x;
    int s = 0;
#pragma unroll
    for (int j = 0; j < PT; ++j) {
        int idx = base + t * PT + j;
        if (idx < N) s += deg[idx];
    }
    sdata[t] = s;
    __syncthreads();
    for (int off = 128; off > 0; off >>= 1) {
        if (t < off) sdata[t] += sdata[t + off];
        __syncthreads();
    }
    if (t == 0) partials[blockIdx.x] = sdata[0];
}

__global__ void scan_partials_kernel(int* partials, int nchunks, int* row_ptr, int N, int E) {
    if (threadIdx.x == 0 && blockIdx.x == 0) {
        int s = 0;
        for (int i = 0; i < nchunks; ++i) { int v = partials[i]; partials[i] = s; s += v; }
        row_ptr[N] = E;
    }
}

__global__ void chunk_scan_kernel(const int* __restrict__ deg, int N,
                                  const int* __restrict__ partials, int* __restrict__ row_ptr) {
    __shared__ int sdata[256];
    constexpr int PT = SCAN_CHUNK / 256;
    int base = blockIdx.x * SCAN_CHUNK;
    int t = threadIdx.x;
    int vals[PT];
    int s = 0;
#pragma unroll
    for (int j = 0; j < PT; ++j) {
        int idx = base + t * PT + j;
        int v = (idx < N) ? deg[idx] : 0;
        vals[j] = s;
        s += v;
    }
    sdata[t] = s;
    __syncthreads();
    for (int off = 1; off < 256; off <<= 1) {
        int v = (t >= off) ? sdata[t - off] : 0;
        __syncthreads();
        sdata[t] += v;
        __syncthreads();
    }
    int texcl = (t > 0) ? sdata[t - 1] : 0;
    int off0 = partials[blockIdx.x];
#pragma unroll
    for (int j = 0; j < PT; ++j) {
        int idx = base + t * PT + j;
        if (idx < N) row_ptr[idx] = off0 + texcl + vals[j];
    }
}

// ---------------- fused: CSR fill (no atomics) + feature convert/scale ----------------
// blocks [0, fillBlocks): edge_src[row_ptr[d] + rank] = s
// blocks [fillBlocks, ...): g0 = ns*feat (fp16), f0g = 0.1*ns*feat (fp16)
__global__ void fill_cvt_kernel(const int* __restrict__ src, const int* __restrict__ dst,
                                const int* __restrict__ rank, const int* __restrict__ row_ptr,
                                unsigned* __restrict__ edge_src, int E, int fillBlocks,
                                const float* __restrict__ features, const float* __restrict__ ns,
                                __half* __restrict__ g0, __half* __restrict__ f0g, int N) {
    int b = blockIdx.x;
    if (b < fillBlocks) {
        int i = b * blockDim.x + threadIdx.x;
        int base = i * 4;
        if (base + 3 < E) {
            int4 s4 = *(const int4*)(src + base);
            int4 d4 = *(const int4*)(dst + base);
            int4 r4 = *(const int4*)(rank + base);
            edge_src[row_ptr[d4.x] + r4.x] = (unsigned)s4.x;
            edge_src[row_ptr[d4.y] + r4.y] = (unsigned)s4.y;
            edge_src[row_ptr[d4.z] + r4.z] = (unsigned)s4.z;
            edge_src[row_ptr[d4.w] + r4.w] = (unsigned)s4.w;
        } else {
            for (int j = base; j < E; ++j)
                edge_src[row_ptr[dst[j]] + rank[j]] = (unsigned)src[j];
        }
    } else {
        int t = (b - fillBlocks) * blockDim.x + threadIdx.x;  // covers 8 floats each
        if (t < N * (D_FEAT / 8)) {
            int node = t >> 3;
            float s = ns[node];
            float4 a = *((const float4*)features + 2 * t);
            float4 c = *((const float4*)features + 2 * t + 1);
            __half2 og[4], of[4];
        og[0] = __float22half2_rn(make_float2(s * a.x, s * a.y));
        og[1] = __float22half2_rn(make_float2(s * a.z, s * a.w));
        og[2] = __float22half2_rn(make_float2(s * c.x, s * c.y));
        og[3] = __float22half2_rn(make_float2(s * c.z, s * c.w));
        float sf = 0.1f * s;
        of[0] = __float22half2_rn(make_float2(sf * a.x, sf * a.y));
        of[1] = __float22half2_rn(make_float2(sf * a.z, sf * a.w));
        of[2] = __float22half2_rn(make_float2(sf * c.x, sf * c.y));
        of[3] = __float22half2_rn(make_float2(sf * c.z, sf * c.w));
            *((float4*)g0 + t)  = *(const float4*)og;
            *((float4*)f0g + t) = *(const float4*)of;
        }
    }
}

// ---------------- propagation (g = ns*h fp16, 4B edge records) ----------------
// One wave per node. 8 groups x 8 lanes; 8 lanes x float4 = one 128B fp16 row.
// g_new = c[node]*agg + f0g[node];   LAST: out = 0.9*nd[node]*agg + 0.1*features[node]
template <bool LAST>
__global__ __launch_bounds__(256) void prop_kernel(
    const __half* __restrict__ g, const __half* __restrict__ f0g,
    const float* __restrict__ features,
    const unsigned* __restrict__ edge_src, const int* __restrict__ row_ptr,
    const float* __restrict__ cvec, const float* __restrict__ nd,
    void* __restrict__ out, int N)
{
    int gid  = blockIdx.x * blockDim.x + threadIdx.x;
    int node = gid >> 6;
    if (node >= N) return;
    int lane = threadIdx.x & 63;
    int grp  = lane >> 3;   // 0..7 : which edge of the octet
    int fl   = lane & 7;    // float4 slot within the 128B node row

    int start = row_ptr[node];
    int end   = row_ptr[node + 1];

    float acc[8];
#pragma unroll
    for (int j = 0; j < 8; ++j) acc[j] = 0.f;

    int e = start + grp;
    for (; e + 8 < end; e += 16) {  // 2 edges per group per iter = 16 edges/wave
        unsigned s0 = edge_src[e];
        unsigned s1 = edge_src[e + 8];
        float4 v0 = *((const float4*)(g + ((size_t)s0 << 6)) + fl);
        float4 v1 = *((const float4*)(g + ((size_t)s1 << 6)) + fl);
        const __half2* p0 = (const __half2*)&v0;
        const __half2* p1 = (const __half2*)&v1;
#pragma unroll
        for (int k = 0; k < 4; ++k) {
            float2 f0 = __half22float2(p0[k]);
            float2 f1 = __half22float2(p1[k]);
            acc[2 * k]     += f0.x + f1.x;
            acc[2 * k + 1] += f0.y + f1.y;
        }
    }
    if (e < end) {
        unsigned s0 = edge_src[e];
        float4 v0 = *((const float4*)(g + ((size_t)s0 << 6)) + fl);
        const __half2* p0 = (const __half2*)&v0;
#pragma unroll
        for (int k = 0; k < 4; ++k) {
            float2 f0 = __half22float2(p0[k]);
            acc[2 * k]     += f0.x;
            acc[2 * k + 1] += f0.y;
        }
    }

    // reduce across the 8 groups
#pragma unroll
    for (int j = 0; j < 8; ++j) acc[j] += __shfl_xor(acc[j], 8, 64);
#pragma unroll
    for (int j = 0; j < 8; ++j) acc[j] += __shfl_xor(acc[j], 16, 64);
#pragma unroll
    for (int j = 0; j < 8; ++j) acc[j] += __shfl_xor(acc[j], 32, 64);

    if (grp == 0) {
        if (!LAST) {
            float cm = cvec[node];
            float4 braw = *((const float4*)(f0g + ((size_t)node << 6)) + fl);
            const __half2* bp = (const __half2*)&braw;
            __half2 o[4];
#pragma unroll
            for (int k = 0; k < 4; ++k) {
                float2 f = __half22float2(bp[k]);
                o[k] = __float22half2_rn(make_float2(fmaf(cm, acc[2 * k], f.x),
                                                     fmaf(cm, acc[2 * k + 1], f.y)));
            }
            *((float4*)((__half*)out + ((size_t)node << 6)) + fl) = *(const float4*)o;
        } else {
            float w = 0.9f * nd[node];
            const float4* fp = (const float4*)(features + ((size_t)node << 6));
            float4 b0 = fp[2 * fl];
            float4 b1 = fp[2 * fl + 1];
            float4 o0, o1;
            o0.x = fmaf(w, acc[0], 0.1f * b0.x);
            o0.y = fmaf(w, acc[1], 0.1f * b0.y);
            o0.z = fmaf(w, acc[2], 0.1f * b0.z);
            o0.w = fmaf(w, acc[3], 0.1f * b0.w);
            o1.x = fmaf(w, acc[4], 0.1f * b1.x);
            o1.y = fmaf(w, acc[5], 0.1f * b1.y);
            o1.z = fmaf(w, acc[6], 0.1f * b1.z);
            o1.w = fmaf(w, acc[7], 0.1f * b1.w);
            float4* op = (float4*)((float*)out + ((size_t)node << 6));
            op[2 * fl]     = o0;
            op[2 * fl + 1] = o1;
        }
    }
}

extern "C" void kernel_launch(void* const* d_in, const int* in_sizes, int n_in,
                              void* d_out, int out_size, void* d_ws, size_t ws_size,
                              hipStream_t stream) {
    const float* features = (const float*)d_in[0];
    const int*   src      = (const int*)d_in[1];
    const int*   dst      = (const int*)d_in[2];
    const int E = in_sizes[1];
    const int N = in_sizes[0] / D_FEAT;

    // ---- workspace layout ----
    char* ws = (char*)d_ws;
    size_t off = 0;
    auto alloc = [&](size_t bytes, size_t align) -> char* {
        off = (off + align - 1) & ~(align - 1);
        char* p = ws + off;
        off += bytes;
        return p;
    };
    int*      deg_out  = (int*)alloc(4 * (size_t)N, 4);
    int*      deg_in   = (int*)alloc(4 * (size_t)N, 4);
    int*      row_ptr  = (int*)alloc(4 * ((size_t)N + 1), 4);
    float*    ns       = (float*)alloc(4 * (size_t)N, 4);
    float*    nd       = (float*)alloc(4 * (size_t)N, 4);
    float*    cvec     = (float*)alloc(4 * (size_t)N, 4);
    int nchunks = (N + SCAN_CHUNK - 1) / SCAN_CHUNK;
    int*      partials = (int*)alloc(4 * (size_t)nchunks, 4);
    int*      rank     = (int*)alloc(4 * (size_t)E, 16);
    unsigned* edge_src = (unsigned*)alloc(4 * (size_t)E, 16);
    __half*   f0g      = (__half*)alloc(2 * (size_t)N * D_FEAT, 16);
    __half*   gA       = (__half*)alloc(2 * (size_t)N * D_FEAT, 16);
    __half*   gB       = (__half*)alloc(2 * (size_t)N * D_FEAT, 16);

    // deg_out, deg_in contiguous -> single memset
    hipMemsetAsync(deg_out, 0, 4 * (size_t)N * 2, stream);

    int ethreads4 = (E + 3) / 4;
    int eblocks = (ethreads4 + 255) / 256;
    deg_kernel<<<eblocks, 256, 0, stream>>>(src, dst, deg_out, deg_in, rank, E);
    norm_kernel<<<(N + 255) / 256, 256, 0, stream>>>(deg_out, deg_in, ns, nd, cvec, N);
    chunk_sum_kernel<<<nchunks, 256, 0, stream>>>(deg_in, N, partials);
    scan_partials_kernel<<<1, 64, 0, stream>>>(partials, nchunks, row_ptr, N, E);
    chunk_scan_kernel<<<nchunks, 256, 0, stream>>>(deg_in, N, partials, row_ptr);

    int cvtThreads = N * (D_FEAT / 8);
    int cvtBlocks = (cvtThreads + 255) / 256;
    fill_cvt_kernel<<<eblocks + cvtBlocks, 256, 0, stream>>>(
        src, dst, rank, row_ptr, edge_src, E, eblocks, features, ns, gA, f0g, N);

    // ---- K layers: L0 reads gA; ping-pong; L9 (LAST) writes fp32 d_out
    int prop_blocks = (int)(((size_t)N * 64 + 255) / 256);
    const __half* h_in = gA;
    for (int k = 0; k < K_LAYERS - 1; ++k) {
        __half* h_out = (k & 1) ? gA : gB;
        prop_kernel<false><<<prop_blocks, 256, 0, stream>>>(
            h_in, f0g, features, edge_src, row_ptr, cvec, nd, h_out, N);
        h_in = h_out;
    }
    prop_kernel<true><<<prop_blocks, 256, 0, stream>>>(
        h_in, f0g, features, edge_src, row_ptr, cvec, nd, d_out, N);
}